// Round 1
// baseline (592.806 us; speedup 1.0000x reference)
//
#include <hip/hip_runtime.h>

// Problem: B=2, S=2048, D=1024, H=16, DK=64
// out   = attn_mean @ vs @ Wo   (since Wv shared across heads, mean_h(attn_h @ vs) = attn_mean @ vs)
// attn_mean[b,s,t] = (1/H) sum_h exp(score)/denom  -- no max-subtraction (scores bounded ~|2.5|)
#define B_ 2
#define S_ 2048
#define D_ 1024
#define H_ 16
#define DK_ 64

typedef __bf16 bf8 __attribute__((ext_vector_type(8)));
typedef float f4 __attribute__((ext_vector_type(4)));
typedef unsigned short u16x8 __attribute__((ext_vector_type(8)));

__device__ __forceinline__ unsigned short f2bf_bits(float f) {
  // RNE float->bf16 (inputs are finite; no NaN handling needed)
  unsigned int u = __float_as_uint(f);
  return (unsigned short)((u + 0x7fffu + ((u >> 16) & 1u)) >> 16);
}

__device__ __forceinline__ bf8 pack_bf8(f4 lo, f4 hi) {
  u16x8 u;
  u[0] = f2bf_bits(lo[0]); u[1] = f2bf_bits(lo[1]);
  u[2] = f2bf_bits(lo[2]); u[3] = f2bf_bits(lo[3]);
  u[4] = f2bf_bits(hi[0]); u[5] = f2bf_bits(hi[1]);
  u[6] = f2bf_bits(hi[2]); u[7] = f2bf_bits(hi[3]);
  union { u16x8 u; bf8 b; } x; x.u = u; return x.b;
}

__device__ __forceinline__ bf8 ldb(const unsigned short* p) {
  return *reinterpret_cast<const bf8*>(p);
}

#define MFMA(a, b, c) __builtin_amdgcn_mfma_f32_16x16x32_bf16((a), (b), (c), 0, 0, 0)

// ---- weight transpose-casts (one-time, tiny) ----
// Wq/Wk [H][D][DK] -> [H][DK][D] bf16
__global__ void k_tw_qk(const float* __restrict__ wq, const float* __restrict__ wk,
                        unsigned short* __restrict__ wqt, unsigned short* __restrict__ wkt) {
  int i = blockIdx.x * 256 + threadIdx.x;       // H*DK*D = 1,048,576
  int h = i >> 16, rem = i & 65535, n = rem >> 10, d = rem & 1023;
  long src = ((long)h << 16) + d * 64 + n;
  wqt[i] = f2bf_bits(wq[src]);
  wkt[i] = f2bf_bits(wk[src]);
}
// Wv [D][DK] -> [DK][D] bf16 ; Wo [DK][D] -> [D][DK] bf16
__global__ void k_tw_vo(const float* __restrict__ wv, const float* __restrict__ wo,
                        unsigned short* __restrict__ wvt, unsigned short* __restrict__ wot) {
  int i = blockIdx.x * 256 + threadIdx.x;       // 65,536
  int n = i >> 10, d = i & 1023;
  wvt[i] = f2bf_bits(wv[d * 64 + n]);
  int dd = i >> 6, kk = i & 63;
  wot[i] = f2bf_bits(wo[kk * 1024 + dd]);
}

// ---- per-head Q/K projection: qs[b,h,s,dk] (qs scaled by log2e/8), ks[b,h,s,dk], bf16 ----
// grid (32 s-tiles, H, which*2+b), block 256 (4 waves x 16 rows x 64 cols, K=1024)
__global__ __launch_bounds__(256) void k_proj_qk(
    const float* __restrict__ q, const float* __restrict__ k,
    const unsigned short* __restrict__ wqt, const unsigned short* __restrict__ wkt,
    unsigned short* __restrict__ qs, unsigned short* __restrict__ ks) {
  const int tid = threadIdx.x, wave = tid >> 6, lane = tid & 63;
  const int l15 = lane & 15, quad = lane >> 4;
  const int stile = blockIdx.x, h = blockIdx.y, zb = blockIdx.z;
  const int which = zb >> 1, b = zb & 1;
  const float* x = which ? k : q;
  const unsigned short* wt = which ? wkt : wqt;
  unsigned short* outp = which ? ks : qs;
  const float scale = which ? 1.0f : 0.18033688011112042f;  // log2(e)/8 folded into qs
  const int s0 = stile * 64 + wave * 16;

  const float* arow = x + ((long)b * S_ + s0 + l15) * D_ + quad * 8;
  const unsigned short* wbase = wt + (long)h * DK_ * D_ + quad * 8;

  f4 acc[4];
  for (int i = 0; i < 4; ++i) acc[i] = f4{0.f, 0.f, 0.f, 0.f};

  for (int k0 = 0; k0 < D_; k0 += 32) {
    f4 alo = *reinterpret_cast<const f4*>(arow + k0);
    f4 ahi = *reinterpret_cast<const f4*>(arow + k0 + 4);
    bf8 a = pack_bf8(alo, ahi);
#pragma unroll
    for (int i = 0; i < 4; ++i) {
      bf8 bf = ldb(wbase + (long)(i * 16 + l15) * D_ + k0);
      acc[i] = MFMA(a, bf, acc[i]);
    }
  }
  unsigned short* obase = outp + (long)(b * H_ + h) * S_ * DK_;
#pragma unroll
  for (int i = 0; i < 4; ++i)
#pragma unroll
    for (int r = 0; r < 4; ++r)
      obase[(long)(s0 + quad * 4 + r) * DK_ + i * 16 + l15] = f2bf_bits(acc[i][r] * scale);
}

// ---- shared V projection, stored transposed bf16: vst[b][dk][t] ----
__global__ __launch_bounds__(256) void k_proj_v(
    const float* __restrict__ v, const unsigned short* __restrict__ wvt,
    unsigned short* __restrict__ vst) {
  const int tid = threadIdx.x, wave = tid >> 6, lane = tid & 63;
  const int l15 = lane & 15, quad = lane >> 4;
  const int stile = blockIdx.x, b = blockIdx.y;
  const int s0 = stile * 64 + wave * 16;
  const float* arow = v + ((long)b * S_ + s0 + l15) * D_ + quad * 8;
  const unsigned short* wbase = wvt + quad * 8;
  f4 acc[4];
  for (int i = 0; i < 4; ++i) acc[i] = f4{0.f, 0.f, 0.f, 0.f};
  for (int k0 = 0; k0 < D_; k0 += 32) {
    f4 alo = *reinterpret_cast<const f4*>(arow + k0);
    f4 ahi = *reinterpret_cast<const f4*>(arow + k0 + 4);
    bf8 a = pack_bf8(alo, ahi);
#pragma unroll
    for (int i = 0; i < 4; ++i) {
      bf8 bf = ldb(wbase + (long)(i * 16 + l15) * D_ + k0);
      acc[i] = MFMA(a, bf, acc[i]);
    }
  }
#pragma unroll
  for (int i = 0; i < 4; ++i)
#pragma unroll
    for (int r = 0; r < 4; ++r)
      vst[((long)b * DK_ + i * 16 + l15) * S_ + s0 + quad * 4 + r] = f2bf_bits(acc[i][r]);
}

// ---- pass 1: recip[b,h,s] = 1/(H * sum_t exp2(qs.ks)) ----
// grid (32 s-tiles, H, B), block 256
__global__ __launch_bounds__(256) void k_denom(
    const unsigned short* __restrict__ qs, const unsigned short* __restrict__ ks,
    float* __restrict__ recip) {
  const int tid = threadIdx.x, wave = tid >> 6, lane = tid & 63;
  const int l15 = lane & 15, quad = lane >> 4;
  const int stile = blockIdx.x, h = blockIdx.y, b = blockIdx.z;
  const int s0 = stile * 64 + wave * 16;
  const unsigned short* qrow = qs + ((long)(b * H_ + h) * S_ + s0 + l15) * DK_ + quad * 8;
  bf8 a0 = ldb(qrow);
  bf8 a1 = ldb(qrow + 32);
  const unsigned short* kbase = ks + (long)(b * H_ + h) * S_ * DK_ + quad * 8;
  f4 sum = f4{0.f, 0.f, 0.f, 0.f};
  for (int t0 = 0; t0 < S_; t0 += 16) {
    const unsigned short* kp = kbase + (long)(t0 + l15) * DK_;
    bf8 b0 = ldb(kp);
    bf8 b1 = ldb(kp + 32);
    f4 d = f4{0.f, 0.f, 0.f, 0.f};
    d = MFMA(a0, b0, d);
    d = MFMA(a1, b1, d);
#pragma unroll
    for (int r = 0; r < 4; ++r) sum[r] += __builtin_amdgcn_exp2f(d[r]);
  }
#pragma unroll
  for (int m = 1; m < 16; m <<= 1) {
#pragma unroll
    for (int r = 0; r < 4; ++r) sum[r] += __shfl_xor(sum[r], m, 64);
  }
  if (l15 == 0) {
    float* rp = recip + (long)(b * H_ + h) * S_ + s0 + quad * 4;
#pragma unroll
    for (int r = 0; r < 4; ++r) rp[r] = 1.0f / (16.0f * sum[r]);
  }
}

// ---- pass 2: attn_mean[b,s,t] = sum_h recip[b,h,s]*exp2(score) ----
// grid (8 t-chunks of 256, 32 s-tiles, B), block 256
__global__ __launch_bounds__(256) void k_attn(
    const unsigned short* __restrict__ qs, const unsigned short* __restrict__ ks,
    const float* __restrict__ recip, float* __restrict__ am) {
  const int tid = threadIdx.x, wave = tid >> 6, lane = tid & 63;
  const int l15 = lane & 15, quad = lane >> 4;
  const int tchunk = blockIdx.x, stile = blockIdx.y, b = blockIdx.z;
  const int s0 = stile * 64 + wave * 16;
  const int t0c = tchunk * 256;

  f4 acc[16];
#pragma unroll
  for (int tt = 0; tt < 16; ++tt) acc[tt] = f4{0.f, 0.f, 0.f, 0.f};

  const unsigned short* qbase = qs + ((long)b * H_ * S_ + s0 + l15) * DK_ + quad * 8;
  const unsigned short* kbase = ks + (long)b * H_ * S_ * DK_ + (long)(t0c + l15) * DK_ + quad * 8;

  for (int h = 0; h < H_; ++h) {
    const unsigned short* qp = qbase + (long)h * S_ * DK_;
    bf8 a0 = ldb(qp);
    bf8 a1 = ldb(qp + 32);
    f4 rp = *reinterpret_cast<const f4*>(recip + (long)(b * H_ + h) * S_ + s0 + quad * 4);
    const unsigned short* kp0 = kbase + (long)h * S_ * DK_;
    for (int tt = 0; tt < 16; ++tt) {
      const unsigned short* kp = kp0 + tt * 16 * DK_;
      bf8 b0 = ldb(kp);
      bf8 b1 = ldb(kp + 32);
      f4 d = f4{0.f, 0.f, 0.f, 0.f};
      d = MFMA(a0, b0, d);
      d = MFMA(a1, b1, d);
#pragma unroll
      for (int r = 0; r < 4; ++r) acc[tt][r] += rp[r] * __builtin_amdgcn_exp2f(d[r]);
    }
  }
  float* obase = am + ((long)b * S_ + s0 + quad * 4) * S_ + t0c + l15;
#pragma unroll
  for (int tt = 0; tt < 16; ++tt)
#pragma unroll
    for (int r = 0; r < 4; ++r) obase[(long)r * S_ + tt * 16] = acc[tt][r];
}

// ---- head = attn_mean @ vs (bf16 out for final MFMA) ----
// grid (32 s-tiles, B), block 256
__global__ __launch_bounds__(256) void k_head(
    const float* __restrict__ am, const unsigned short* __restrict__ vst,
    unsigned short* __restrict__ head) {
  const int tid = threadIdx.x, wave = tid >> 6, lane = tid & 63;
  const int l15 = lane & 15, quad = lane >> 4;
  const int stile = blockIdx.x, b = blockIdx.y;
  const int s0 = stile * 64 + wave * 16;
  const float* arow = am + ((long)b * S_ + s0 + l15) * S_ + quad * 8;
  const unsigned short* vb = vst + (long)b * DK_ * S_ + quad * 8;
  f4 acc[4];
  for (int i = 0; i < 4; ++i) acc[i] = f4{0.f, 0.f, 0.f, 0.f};
  for (int t0 = 0; t0 < S_; t0 += 32) {
    f4 alo = *reinterpret_cast<const f4*>(arow + t0);
    f4 ahi = *reinterpret_cast<const f4*>(arow + t0 + 4);
    bf8 a = pack_bf8(alo, ahi);
#pragma unroll
    for (int i = 0; i < 4; ++i) {
      bf8 bf = ldb(vb + (long)(i * 16 + l15) * S_ + t0);
      acc[i] = MFMA(a, bf, acc[i]);
    }
  }
#pragma unroll
  for (int i = 0; i < 4; ++i)
#pragma unroll
    for (int r = 0; r < 4; ++r)
      head[((long)b * S_ + s0 + quad * 4 + r) * DK_ + i * 16 + l15] = f2bf_bits(acc[i][r]);
}

// ---- out = head @ Wo ----
// grid (4 d-chunks of 256, 32 s-tiles, B), block 256
__global__ __launch_bounds__(256) void k_out(
    const unsigned short* __restrict__ head, const unsigned short* __restrict__ wot,
    float* __restrict__ out) {
  const int tid = threadIdx.x, wave = tid >> 6, lane = tid & 63;
  const int l15 = lane & 15, quad = lane >> 4;
  const int dchunk = blockIdx.x, stile = blockIdx.y, b = blockIdx.z;
  const int s0 = stile * 64 + wave * 16;
  const int n0 = dchunk * 256;
  const unsigned short* hrow = head + ((long)b * S_ + s0 + l15) * DK_ + quad * 8;
  bf8 a0 = ldb(hrow);
  bf8 a1 = ldb(hrow + 32);
  const unsigned short* wb = wot + quad * 8;
  float* obase = out + ((long)b * S_ + s0 + quad * 4) * D_ + n0 + l15;
#pragma unroll
  for (int i = 0; i < 16; ++i) {
    const unsigned short* wp = wb + (long)(n0 + i * 16 + l15) * DK_;
    bf8 b0 = ldb(wp);
    bf8 b1 = ldb(wp + 32);
    f4 d = f4{0.f, 0.f, 0.f, 0.f};
    d = MFMA(a0, b0, d);
    d = MFMA(a1, b1, d);
#pragma unroll
    for (int r = 0; r < 4; ++r) obase[(long)r * D_ + i * 16] = d[r];
  }
}

extern "C" void kernel_launch(void* const* d_in, const int* in_sizes, int n_in,
                              void* d_out, int out_size, void* d_ws, size_t ws_size,
                              hipStream_t stream) {
  const float* q  = (const float*)d_in[0];
  const float* k  = (const float*)d_in[1];
  const float* v  = (const float*)d_in[2];
  const float* Wq = (const float*)d_in[3];
  const float* Wk = (const float*)d_in[4];
  const float* Wv = (const float*)d_in[5];
  const float* Wo = (const float*)d_in[6];

  float* out = (float*)d_out;                       // [B,S,D] = 4,194,304 floats
  float* am  = out + (long)B_ * S_ * D_;            // [B,S,S] = 8,388,608 floats

  // workspace carve-up (~21.8 MB total)
  unsigned short* qs   = (unsigned short*)d_ws;     // B*H*S*DK
  unsigned short* ksb  = qs  + 4194304;             // B*H*S*DK
  unsigned short* wqt  = ksb + 4194304;             // H*DK*D
  unsigned short* wkt  = wqt + 1048576;
  unsigned short* wvt  = wkt + 1048576;             // DK*D
  unsigned short* wot  = wvt + 65536;               // D*DK
  unsigned short* vst  = wot + 65536;               // B*DK*S
  unsigned short* headb= vst + 262144;              // B*S*DK
  float* recip = (float*)(headb + 262144);          // B*H*S

  k_tw_qk<<<4096, 256, 0, stream>>>(Wq, Wk, wqt, wkt);
  k_tw_vo<<<256, 256, 0, stream>>>(Wv, Wo, wvt, wot);
  k_proj_qk<<<dim3(32, 16, 4), 256, 0, stream>>>(q, k, wqt, wkt, qs, ksb);
  k_proj_v<<<dim3(32, 2), 256, 0, stream>>>(v, wvt, vst);
  k_denom<<<dim3(32, 16, 2), 256, 0, stream>>>(qs, ksb, recip);
  k_attn<<<dim3(8, 32, 2), 256, 0, stream>>>(qs, ksb, recip, am);
  k_head<<<dim3(32, 2), 256, 0, stream>>>(am, vst, headb);
  k_out<<<dim3(4, 32, 2), 256, 0, stream>>>(headb, wot, out);
}

// Round 2
// 298.920 us; speedup vs baseline: 1.9832x; 1.9832x over previous
//
#include <hip/hip_runtime.h>

// B=2, S=2048, D=1024, H=16, DK=64
// out = attn_mean @ vs @ Wo  (Wv shared across heads => mean_h(attn_h @ vs) = attn_mean @ vs)
// attn_mean[b,s,t] = (1/H) sum_h exp(score)/denom  -- no max-subtraction (scores bounded ~|2.5|)
// qs/ks layout: [b*S+s][h*64+dk]  (concatenated-head GEMM output)
#define B_ 2
#define S_ 2048
#define D_ 1024
#define H_ 16
#define DK_ 64

typedef __bf16 bf8 __attribute__((ext_vector_type(8)));
typedef float f4 __attribute__((ext_vector_type(4)));
typedef unsigned short u16x8 __attribute__((ext_vector_type(8)));

__device__ __forceinline__ unsigned short f2bf_bits(float f) {
  unsigned int u = __float_as_uint(f);
  return (unsigned short)((u + 0x7fffu + ((u >> 16) & 1u)) >> 16);
}

__device__ __forceinline__ bf8 pack_bf8(f4 lo, f4 hi) {
  u16x8 u;
  u[0] = f2bf_bits(lo[0]); u[1] = f2bf_bits(lo[1]);
  u[2] = f2bf_bits(lo[2]); u[3] = f2bf_bits(lo[3]);
  u[4] = f2bf_bits(hi[0]); u[5] = f2bf_bits(hi[1]);
  u[6] = f2bf_bits(hi[2]); u[7] = f2bf_bits(hi[3]);
  union { u16x8 u; bf8 b; } x; x.u = u; return x.b;
}

__device__ __forceinline__ bf8 ldb(const unsigned short* p) {
  return *reinterpret_cast<const bf8*>(p);
}

// async global->LDS, 16B per lane; LDS dest must be wave-uniform base + lane*16
__device__ __forceinline__ void stage16(const void* g, void* l) {
  __builtin_amdgcn_global_load_lds(
      (const __attribute__((address_space(1))) void*)g,
      (__attribute__((address_space(3))) void*)l, 16, 0, 0);
}

#define MFMA(a, b, c) __builtin_amdgcn_mfma_f32_16x16x32_bf16((a), (b), (c), 0, 0, 0)

// ---- cast q,k f32 -> bf16 rows [4096][1024] ----
__global__ void k_cast(const float* __restrict__ q, const float* __restrict__ k,
                       unsigned short* __restrict__ qb, unsigned short* __restrict__ kb) {
  long i = ((long)blockIdx.x * 256 + threadIdx.x) * 8;
  const float* src = blockIdx.y ? k : q;
  unsigned short* dst = blockIdx.y ? kb : qb;
  f4 lo = *reinterpret_cast<const f4*>(src + i);
  f4 hi = *reinterpret_cast<const f4*>(src + i + 4);
  *reinterpret_cast<bf8*>(dst + i) = pack_bf8(lo, hi);
}

// ---- weight transpose-casts (tiny) ----
// Wq/Wk [H][D][DK] -> Wt[n=h*64+dk][d] bf16  (B^T layout for NT GEMM)
__global__ void k_tw_qk(const float* __restrict__ wq, const float* __restrict__ wk,
                        unsigned short* __restrict__ wqt, unsigned short* __restrict__ wkt) {
  int i = blockIdx.x * 256 + threadIdx.x;       // H*DK*D = 1,048,576
  int h = i >> 16, rem = i & 65535, n = rem >> 10, d = rem & 1023;
  long src = ((long)h << 16) + d * 64 + n;
  wqt[i] = f2bf_bits(wq[src]);
  wkt[i] = f2bf_bits(wk[src]);
}
// Wv [D][DK] -> [DK][D] bf16 ; Wo [DK][D] -> [D][DK] bf16
__global__ void k_tw_vo(const float* __restrict__ wv, const float* __restrict__ wo,
                        unsigned short* __restrict__ wvt, unsigned short* __restrict__ wot) {
  int i = blockIdx.x * 256 + threadIdx.x;       // 65,536
  int n = i >> 10, d = i & 1023;
  wvt[i] = f2bf_bits(wv[d * 64 + n]);
  int dd = i >> 6, kk = i & 63;
  wot[i] = f2bf_bits(wo[kk * 1024 + dd]);
}

// ---- m97-style GEMM: C[4096][1024] = X @ W^T, 128x128 tile, BK=32, global_load_lds ----
// grid (32 m-tiles, 8 n-tiles, which), block 256 (4 waves in 2x2, each 64x64 via 4x4 MFMA)
__global__ __launch_bounds__(256) void k_gemm_qk(
    const unsigned short* __restrict__ qb, const unsigned short* __restrict__ kb,
    const unsigned short* __restrict__ wqt, const unsigned short* __restrict__ wkt,
    unsigned short* __restrict__ qsb, unsigned short* __restrict__ ksb) {
  __shared__ unsigned short lds[8192];          // A 128x32 @0, B 128x32 @4096 (shorts)
  const int tid = threadIdx.x, wave = tid >> 6, lane = tid & 63;
  const int l15 = lane & 15, quad = lane >> 4;
  const int m0 = blockIdx.x * 128, n0 = blockIdx.y * 128;
  const int which = blockIdx.z;
  const unsigned short* A = which ? kb : qb;
  const unsigned short* W = which ? wkt : wqt;
  unsigned short* C = which ? ksb : qsb;
  const float scale = which ? 1.0f : 0.18033688011112042f;  // log2(e)/8 folded into qs
  const int wr = wave >> 1, wc = wave & 1;

  f4 acc[4][4];
#pragma unroll
  for (int i = 0; i < 4; ++i)
#pragma unroll
    for (int j = 0; j < 4; ++j) acc[i][j] = f4{0.f, 0.f, 0.f, 0.f};

  const int srow = tid >> 2, schunk = (tid & 3) * 8;
  const unsigned short* ga0 = A + (long)(m0 + srow) * D_ + schunk;
  const unsigned short* gb0 = W + (long)(n0 + srow) * D_ + schunk;

  for (int k0 = 0; k0 < D_; k0 += 32) {
    stage16(ga0 + k0, lds + tid * 8);
    stage16(ga0 + 64 * D_ + k0, lds + 2048 + tid * 8);
    stage16(gb0 + k0, lds + 4096 + tid * 8);
    stage16(gb0 + 64 * D_ + k0, lds + 6144 + tid * 8);
    __syncthreads();
    bf8 aF[4], bF[4];
#pragma unroll
    for (int mi = 0; mi < 4; ++mi)
      aF[mi] = ldb(lds + (wr * 64 + mi * 16 + l15) * 32 + quad * 8);
#pragma unroll
    for (int ni = 0; ni < 4; ++ni)
      bF[ni] = ldb(lds + 4096 + (wc * 64 + ni * 16 + l15) * 32 + quad * 8);
#pragma unroll
    for (int mi = 0; mi < 4; ++mi)
#pragma unroll
      for (int ni = 0; ni < 4; ++ni)
        acc[mi][ni] = MFMA(aF[mi], bF[ni], acc[mi][ni]);
    __syncthreads();
  }
#pragma unroll
  for (int mi = 0; mi < 4; ++mi)
#pragma unroll
    for (int r = 0; r < 4; ++r) {
      long row = m0 + wr * 64 + mi * 16 + quad * 4 + r;
#pragma unroll
      for (int ni = 0; ni < 4; ++ni)
        C[row * D_ + n0 + wc * 64 + ni * 16 + l15] = f2bf_bits(acc[mi][ni][r] * scale);
    }
}

// ---- shared V projection, stored transposed bf16: vst[b][dk][t] (small, direct) ----
__global__ __launch_bounds__(256) void k_proj_v(
    const float* __restrict__ v, const unsigned short* __restrict__ wvt,
    unsigned short* __restrict__ vst) {
  const int tid = threadIdx.x, wave = tid >> 6, lane = tid & 63;
  const int l15 = lane & 15, quad = lane >> 4;
  const int stile = blockIdx.x, b = blockIdx.y;
  const int s0 = stile * 64 + wave * 16;
  const float* arow = v + ((long)b * S_ + s0 + l15) * D_ + quad * 8;
  const unsigned short* wbase = wvt + quad * 8;
  f4 acc[4];
  for (int i = 0; i < 4; ++i) acc[i] = f4{0.f, 0.f, 0.f, 0.f};
  for (int k0 = 0; k0 < D_; k0 += 32) {
    f4 alo = *reinterpret_cast<const f4*>(arow + k0);
    f4 ahi = *reinterpret_cast<const f4*>(arow + k0 + 4);
    bf8 a = pack_bf8(alo, ahi);
#pragma unroll
    for (int i = 0; i < 4; ++i) {
      bf8 bf = ldb(wbase + (long)(i * 16 + l15) * D_ + k0);
      acc[i] = MFMA(a, bf, acc[i]);
    }
  }
#pragma unroll
  for (int i = 0; i < 4; ++i)
#pragma unroll
    for (int r = 0; r < 4; ++r)
      vst[((long)b * DK_ + i * 16 + l15) * S_ + s0 + quad * 4 + r] = f2bf_bits(acc[i][r]);
}

// ---- pass 1: recip[b,h,s] = 1/(H * sum_t exp2(qs.ks)) ----
// grid (8 s-tiles of 256, H, B), block 1024 (16 waves x 16 rows); K-chunks of 128 staged to LDS
__global__ __launch_bounds__(1024) void k_denom(
    const unsigned short* __restrict__ qsb, const unsigned short* __restrict__ ksb,
    float* __restrict__ recip) {
  __shared__ unsigned short lds[8192];          // two half-tiles 128x32 shorts
  const int tid = threadIdx.x, wave = tid >> 6, lane = tid & 63;
  const int l15 = lane & 15, quad = lane >> 4;
  const int stile = blockIdx.x, h = blockIdx.y, b = blockIdx.z;
  const int s0 = stile * 256 + wave * 16;

  const unsigned short* qrow = qsb + ((long)(b * S_) + s0 + l15) * D_ + h * 64 + quad * 8;
  bf8 a0 = ldb(qrow);
  bf8 a1 = ldb(qrow + 32);

  // staging map: tid*8 shorts linear; h2=tid>>9, r=(tid>>2)&127, c=tid&3
  const int h2 = tid >> 9, r_ = (tid >> 2) & 127, c_ = tid & 3;
  const unsigned short* gsrc0 = ksb + ((long)(b * S_) + r_) * D_ + h * 64 + h2 * 32 + c_ * 8;

  f4 sum = f4{0.f, 0.f, 0.f, 0.f};
  for (int t0 = 0; t0 < S_; t0 += 128) {
    stage16(gsrc0 + (long)t0 * D_, lds + tid * 8);
    __syncthreads();
#pragma unroll
    for (int tt = 0; tt < 8; ++tt) {
      bf8 b0 = ldb(lds + (tt * 16 + l15) * 32 + quad * 8);
      bf8 b1 = ldb(lds + 4096 + (tt * 16 + l15) * 32 + quad * 8);
      f4 d = f4{0.f, 0.f, 0.f, 0.f};
      d = MFMA(a0, b0, d);
      d = MFMA(a1, b1, d);
#pragma unroll
      for (int r = 0; r < 4; ++r) sum[r] += __builtin_amdgcn_exp2f(d[r]);
    }
    __syncthreads();
  }
#pragma unroll
  for (int m = 1; m < 16; m <<= 1) {
#pragma unroll
    for (int r = 0; r < 4; ++r) sum[r] += __shfl_xor(sum[r], m, 64);
  }
  if (l15 == 0) {
    float* rp = recip + (long)(b * H_ + h) * S_ + s0 + quad * 4;
#pragma unroll
    for (int r = 0; r < 4; ++r) rp[r] = 1.0f / (16.0f * sum[r]);
  }
}

// ---- pass 2: attn_mean[b,s,t] = sum_h recip[b,h,s]*exp2(score) ----
// grid (8 t-chunks of 256, 32 s-tiles of 64, B), block 256; per-h K-chunk staged to LDS
__global__ __launch_bounds__(256) void k_attn(
    const unsigned short* __restrict__ qsb, const unsigned short* __restrict__ ksb,
    const float* __restrict__ recip, float* __restrict__ am) {
  __shared__ unsigned short lds[16384];         // two half-tiles 256x32 shorts
  const int tid = threadIdx.x, wave = tid >> 6, lane = tid & 63;
  const int l15 = lane & 15, quad = lane >> 4;
  const int tchunk = blockIdx.x, stile = blockIdx.y, b = blockIdx.z;
  const int s0 = stile * 64 + wave * 16;
  const int t0c = tchunk * 256;

  f4 acc[16];
#pragma unroll
  for (int tt = 0; tt < 16; ++tt) acc[tt] = f4{0.f, 0.f, 0.f, 0.f};

  const unsigned short* qbase = qsb + ((long)(b * S_) + s0 + l15) * D_ + quad * 8;

  for (int h = 0; h < H_; ++h) {
    // stage ks chunk [256 t x 64 dk] for this head: 8 issues x 256 thr x 16B = 32 KB
#pragma unroll
    for (int i = 0; i < 8; ++i) {
      int h2 = i >> 2, rr = (i & 3) * 64 + (tid >> 2), cc = tid & 3;
      stage16(ksb + ((long)(b * S_) + t0c + rr) * D_ + h * 64 + h2 * 32 + cc * 8,
              lds + i * 2048 + tid * 8);
    }
    __syncthreads();
    bf8 a0 = ldb(qbase + h * 64);
    bf8 a1 = ldb(qbase + h * 64 + 32);
    f4 rp = *reinterpret_cast<const f4*>(recip + (long)(b * H_ + h) * S_ + s0 + quad * 4);
#pragma unroll
    for (int tt = 0; tt < 16; ++tt) {
      bf8 b0 = ldb(lds + (tt * 16 + l15) * 32 + quad * 8);
      bf8 b1 = ldb(lds + 8192 + (tt * 16 + l15) * 32 + quad * 8);
      f4 d = f4{0.f, 0.f, 0.f, 0.f};
      d = MFMA(a0, b0, d);
      d = MFMA(a1, b1, d);
#pragma unroll
      for (int r = 0; r < 4; ++r) acc[tt][r] += rp[r] * __builtin_amdgcn_exp2f(d[r]);
    }
    __syncthreads();
  }
  float* obase = am + ((long)b * S_ + s0 + quad * 4) * S_ + t0c + l15;
#pragma unroll
  for (int tt = 0; tt < 16; ++tt)
#pragma unroll
    for (int r = 0; r < 4; ++r) obase[(long)r * S_ + tt * 16] = acc[tt][r];
}

// ---- head = attn_mean @ vs (bf16 out for final MFMA) ----
__global__ __launch_bounds__(256) void k_head(
    const float* __restrict__ am, const unsigned short* __restrict__ vst,
    unsigned short* __restrict__ head) {
  const int tid = threadIdx.x, wave = tid >> 6, lane = tid & 63;
  const int l15 = lane & 15, quad = lane >> 4;
  const int stile = blockIdx.x, b = blockIdx.y;
  const int s0 = stile * 64 + wave * 16;
  const float* arow = am + ((long)b * S_ + s0 + l15) * S_ + quad * 8;
  const unsigned short* vb = vst + (long)b * DK_ * S_ + quad * 8;
  f4 acc[4];
  for (int i = 0; i < 4; ++i) acc[i] = f4{0.f, 0.f, 0.f, 0.f};
  for (int t0 = 0; t0 < S_; t0 += 32) {
    f4 alo = *reinterpret_cast<const f4*>(arow + t0);
    f4 ahi = *reinterpret_cast<const f4*>(arow + t0 + 4);
    bf8 a = pack_bf8(alo, ahi);
#pragma unroll
    for (int i = 0; i < 4; ++i) {
      bf8 bf = ldb(vb + (long)(i * 16 + l15) * S_ + t0);
      acc[i] = MFMA(a, bf, acc[i]);
    }
  }
#pragma unroll
  for (int i = 0; i < 4; ++i)
#pragma unroll
    for (int r = 0; r < 4; ++r)
      head[((long)b * S_ + s0 + quad * 4 + r) * DK_ + i * 16 + l15] = f2bf_bits(acc[i][r]);
}

// ---- out = head @ Wo ----
__global__ __launch_bounds__(256) void k_out(
    const unsigned short* __restrict__ head, const unsigned short* __restrict__ wot,
    float* __restrict__ out) {
  const int tid = threadIdx.x, wave = tid >> 6, lane = tid & 63;
  const int l15 = lane & 15, quad = lane >> 4;
  const int dchunk = blockIdx.x, stile = blockIdx.y, b = blockIdx.z;
  const int s0 = stile * 64 + wave * 16;
  const int n0 = dchunk * 256;
  const unsigned short* hrow = head + ((long)b * S_ + s0 + l15) * DK_ + quad * 8;
  bf8 a0 = ldb(hrow);
  bf8 a1 = ldb(hrow + 32);
  const unsigned short* wb = wot + quad * 8;
  float* obase = out + ((long)b * S_ + s0 + quad * 4) * D_ + n0 + l15;
#pragma unroll
  for (int i = 0; i < 16; ++i) {
    const unsigned short* wp = wb + (long)(n0 + i * 16 + l15) * DK_;
    bf8 b0 = ldb(wp);
    bf8 b1 = ldb(wp + 32);
    f4 d = f4{0.f, 0.f, 0.f, 0.f};
    d = MFMA(a0, b0, d);
    d = MFMA(a1, b1, d);
#pragma unroll
    for (int r = 0; r < 4; ++r) obase[(long)r * D_ + i * 16] = d[r];
  }
}

extern "C" void kernel_launch(void* const* d_in, const int* in_sizes, int n_in,
                              void* d_out, int out_size, void* d_ws, size_t ws_size,
                              hipStream_t stream) {
  const float* q  = (const float*)d_in[0];
  const float* k  = (const float*)d_in[1];
  const float* v  = (const float*)d_in[2];
  const float* Wq = (const float*)d_in[3];
  const float* Wk = (const float*)d_in[4];
  const float* Wv = (const float*)d_in[5];
  const float* Wo = (const float*)d_in[6];

  float* out = (float*)d_out;                       // [B,S,D]
  float* am  = out + (long)B_ * S_ * D_;            // [B,S,S]

  // workspace (~22.5 MB)
  unsigned short* qsb  = (unsigned short*)d_ws;     // [4096][1024]
  unsigned short* ksb  = qsb + 4194304;
  unsigned short* wqt  = ksb + 4194304;             // [1024][1024]
  unsigned short* wkt  = wqt + 1048576;
  unsigned short* wvt  = wkt + 1048576;             // [64][1024]
  unsigned short* wot  = wvt + 65536;               // [1024][64]
  unsigned short* vst  = wot + 65536;               // [B][64][S]
  unsigned short* headb= vst + 262144;              // [B*S][64]
  float* recip = (float*)(headb + 262144);          // [B*H*S]

  // bf16 copies of q,k live temporarily in the am region of d_out
  // (dead before k_attn writes am)
  unsigned short* qb = (unsigned short*)am;         // [4096][1024]
  unsigned short* kb = qb + 4194304;

  k_cast<<<dim3(2048, 2), 256, 0, stream>>>(q, k, qb, kb);
  k_tw_qk<<<4096, 256, 0, stream>>>(Wq, Wk, wqt, wkt);
  k_tw_vo<<<256, 256, 0, stream>>>(Wv, Wo, wvt, wot);
  k_gemm_qk<<<dim3(32, 8, 2), 256, 0, stream>>>(qb, kb, wqt, wkt, qsb, ksb);
  k_proj_v<<<dim3(32, 2), 256, 0, stream>>>(v, wvt, vst);
  k_denom<<<dim3(8, 16, 2), 1024, 0, stream>>>(qsb, ksb, recip);
  k_attn<<<dim3(8, 32, 2), 256, 0, stream>>>(qsb, ksb, recip, am);
  k_head<<<dim3(32, 2), 256, 0, stream>>>(am, vst, headb);
  k_out<<<dim3(4, 32, 2), 256, 0, stream>>>(headb, wot, out);
}

// Round 3
// 266.148 us; speedup vs baseline: 2.2274x; 1.1231x over previous
//
#include <hip/hip_runtime.h>

// B=2, S=2048, D=1024, H=16, DK=64
// out = attn_mean @ vs @ Wo  (Wv shared across heads => mean_h(attn_h @ vs) = attn_mean @ vs)
// attn_mean[b,s,t] = (1/H) sum_h exp(score)/denom  -- no max-subtraction (scores bounded ~|2.5|)
// qs/ks layout: [b*S+s][h*64+dk]  (concatenated-head GEMM output)
// All LDS tiles are FRAGMENT-MAJOR: 16B-unit index = tile*64 + quad*16 + l15
//   -> reader addr = tilebase + lane*16B, conflict-free for ds_read_b128.
#define B_ 2
#define S_ 2048
#define D_ 1024
#define H_ 16
#define DK_ 64

typedef __bf16 bf8 __attribute__((ext_vector_type(8)));
typedef float f4 __attribute__((ext_vector_type(4)));
typedef unsigned short u16x8 __attribute__((ext_vector_type(8)));

__device__ __forceinline__ unsigned short f2bf_bits(float f) {
  unsigned int u = __float_as_uint(f);
  return (unsigned short)((u + 0x7fffu + ((u >> 16) & 1u)) >> 16);
}

__device__ __forceinline__ bf8 pack_bf8(f4 lo, f4 hi) {
  u16x8 u;
  u[0] = f2bf_bits(lo[0]); u[1] = f2bf_bits(lo[1]);
  u[2] = f2bf_bits(lo[2]); u[3] = f2bf_bits(lo[3]);
  u[4] = f2bf_bits(hi[0]); u[5] = f2bf_bits(hi[1]);
  u[6] = f2bf_bits(hi[2]); u[7] = f2bf_bits(hi[3]);
  union { u16x8 u; bf8 b; } x; x.u = u; return x.b;
}

__device__ __forceinline__ bf8 ldb(const unsigned short* p) {
  return *reinterpret_cast<const bf8*>(p);
}

__device__ __forceinline__ void stage16(const void* g, void* l) {
  __builtin_amdgcn_global_load_lds(
      (const __attribute__((address_space(1))) void*)g,
      (__attribute__((address_space(3))) void*)l, 16, 0, 0);
}

#define MFMA(a, b, c) __builtin_amdgcn_mfma_f32_16x16x32_bf16((a), (b), (c), 0, 0, 0)

// ---- merged prep: cast q,k -> bf16 rows; transpose-cast weights ----
// blocks 0..2047: cast q | 2048..4095: cast k | 4096..8191: tw_qk | 8192..8447: tw_vo
__global__ void k_prep(const float* __restrict__ q, const float* __restrict__ k,
                       const float* __restrict__ wq, const float* __restrict__ wk,
                       const float* __restrict__ wv, const float* __restrict__ wo,
                       unsigned short* __restrict__ qb, unsigned short* __restrict__ kb,
                       unsigned short* __restrict__ wqt, unsigned short* __restrict__ wkt,
                       unsigned short* __restrict__ wvt, unsigned short* __restrict__ wot) {
  int bid = blockIdx.x, tid = threadIdx.x;
  if (bid < 4096) {
    int which = bid >> 11;
    long i = ((long)(bid & 2047) * 256 + tid) * 8;
    const float* src = which ? k : q;
    unsigned short* dst = which ? kb : qb;
    f4 lo = *reinterpret_cast<const f4*>(src + i);
    f4 hi = *reinterpret_cast<const f4*>(src + i + 4);
    *reinterpret_cast<bf8*>(dst + i) = pack_bf8(lo, hi);
  } else if (bid < 8192) {
    int i = (bid - 4096) * 256 + tid;         // H*DK*D = 1,048,576
    int h = i >> 16, rem = i & 65535, n = rem >> 10, d = rem & 1023;
    long src = ((long)h << 16) + d * 64 + n;
    wqt[i] = f2bf_bits(wq[src]);
    wkt[i] = f2bf_bits(wk[src]);
  } else {
    int i = (bid - 8192) * 256 + tid;         // 65,536
    int n = i >> 10, d = i & 1023;
    wvt[i] = f2bf_bits(wv[d * 64 + n]);
    int dd = i >> 6, kk = i & 63;
    wot[i] = f2bf_bits(wo[kk * 1024 + dd]);
  }
}

// ---- GEMM: C[4096][1024] = X @ W^T, 128x64 tile, BK=32, fragment-major LDS ----
// grid (32 m-tiles, 16 n-tiles, which), block 256 (4 waves 2x2; wave = 64m x 32n)
__global__ __launch_bounds__(256) void k_gemm_qk(
    const unsigned short* __restrict__ qb, const unsigned short* __restrict__ kb,
    const unsigned short* __restrict__ wqt, const unsigned short* __restrict__ wkt,
    unsigned short* __restrict__ qsb, unsigned short* __restrict__ ksb) {
  __shared__ unsigned short lds[6144];          // A frags 0..4095 (8 tiles), B frags 4096..6143 (4 tiles)
  const int tid = threadIdx.x, wave = tid >> 6, lane = tid & 63;
  const int l15 = lane & 15, quad = lane >> 4;
  const int m0 = blockIdx.x * 128, n0 = blockIdx.y * 64;
  const int which = blockIdx.z;
  const unsigned short* A = which ? kb : qb;
  const unsigned short* W = which ? wkt : wqt;
  unsigned short* C = which ? ksb : qsb;
  const float scale = which ? 1.0f : 0.18033688011112042f;  // log2(e)/8 folded into qs
  const int wr = wave >> 1, wc = wave & 1;

  f4 acc[4][2];
#pragma unroll
  for (int i = 0; i < 4; ++i)
#pragma unroll
    for (int j = 0; j < 2; ++j) acc[i][j] = f4{0.f, 0.f, 0.f, 0.f};

  // staging decode (u = i*256+tid): l15s=u&15, quads=(u>>4)&3, T=u>>6
  const int sl15 = tid & 15, squad = (tid >> 4) & 3, sT = tid >> 6;  // T low 2 bits

  for (int k0 = 0; k0 < D_; k0 += 32) {
    // A: 8 tiles of 16 rows; calls i=0,1 give T = i*4 + sT
    stage16(A + (long)(m0 + sT * 16 + sl15) * D_ + k0 + squad * 8, lds + tid * 8);
    stage16(A + (long)(m0 + 64 + sT * 16 + sl15) * D_ + k0 + squad * 8, lds + 2048 + tid * 8);
    // B: 4 tiles of 16 rows
    stage16(W + (long)(n0 + sT * 16 + sl15) * D_ + k0 + squad * 8, lds + 4096 + tid * 8);
    __syncthreads();
    bf8 aF[4], bF[2];
#pragma unroll
    for (int mi = 0; mi < 4; ++mi)
      aF[mi] = ldb(lds + (wr * 4 + mi) * 512 + lane * 8);
#pragma unroll
    for (int ni = 0; ni < 2; ++ni)
      bF[ni] = ldb(lds + 4096 + (wc * 2 + ni) * 512 + lane * 8);
#pragma unroll
    for (int mi = 0; mi < 4; ++mi)
#pragma unroll
      for (int ni = 0; ni < 2; ++ni)
        acc[mi][ni] = MFMA(aF[mi], bF[ni], acc[mi][ni]);
    __syncthreads();
  }
#pragma unroll
  for (int mi = 0; mi < 4; ++mi)
#pragma unroll
    for (int r = 0; r < 4; ++r) {
      long row = m0 + wr * 64 + mi * 16 + quad * 4 + r;
#pragma unroll
      for (int ni = 0; ni < 2; ++ni)
        C[row * D_ + n0 + wc * 32 + ni * 16 + l15] = f2bf_bits(acc[mi][ni][r] * scale);
    }
}

// ---- V projection split-K: partial[kc][row][64] f32, kc chunk = 256 ----
// grid (64 rowgroups of 64, 4 kc), block 256
__global__ __launch_bounds__(256) void k_pv(
    const float* __restrict__ v, const unsigned short* __restrict__ wvt,
    float* __restrict__ pv) {
  const int tid = threadIdx.x, wave = tid >> 6, lane = tid & 63;
  const int l15 = lane & 15, quad = lane >> 4;
  const int rg = blockIdx.x, kc = blockIdx.y;
  const int row0 = rg * 64 + wave * 16;
  const float* arow = v + (long)(row0 + l15) * D_ + kc * 256 + quad * 8;
  const unsigned short* wbase = wvt + kc * 256 + quad * 8;
  f4 acc[4];
  for (int i = 0; i < 4; ++i) acc[i] = f4{0.f, 0.f, 0.f, 0.f};
  for (int k0 = 0; k0 < 256; k0 += 32) {
    f4 alo = *reinterpret_cast<const f4*>(arow + k0);
    f4 ahi = *reinterpret_cast<const f4*>(arow + k0 + 4);
    bf8 a = pack_bf8(alo, ahi);
#pragma unroll
    for (int i = 0; i < 4; ++i) {
      bf8 bf = ldb(wbase + (long)(i * 16 + l15) * D_ + k0);
      acc[i] = MFMA(a, bf, acc[i]);
    }
  }
#pragma unroll
  for (int i = 0; i < 4; ++i)
#pragma unroll
    for (int r = 0; r < 4; ++r)
      pv[((long)kc * 4096 + row0 + quad * 4 + r) * 64 + i * 16 + l15] = acc[i][r];
}

// reduce 4 k-partials -> vst[b][dk][t] bf16 (writes coalesced over t)
__global__ void k_vred(const float* __restrict__ pv, unsigned short* __restrict__ vst) {
  int e = blockIdx.x * 256 + threadIdx.x;      // e = (b*64+dk)*2048 + t
  int t = e & 2047, dk = (e >> 11) & 63, b = e >> 17;
  long row = (long)b * S_ + t;
  float s = pv[row * 64 + dk] + pv[(4096 + row) * 64 + dk] +
            pv[(8192 + row) * 64 + dk] + pv[(12288 + row) * 64 + dk];
  vst[e] = f2bf_bits(s);
}

// ---- pass 1: recip[b,h,s] = 1/(H * sum_t exp2(qs.ks)) ----
// grid (8 s-tiles of 256, H, B), block 1024 (16 waves); K-chunks of 128, fragment-major
__global__ __launch_bounds__(1024) void k_denom(
    const unsigned short* __restrict__ qsb, const unsigned short* __restrict__ ksb,
    float* __restrict__ recip) {
  __shared__ unsigned short lds[8192];          // 128 t-rows x 64 dk, fragment-major
  const int tid = threadIdx.x, wave = tid >> 6, lane = tid & 63;
  const int l15 = lane & 15, quad = lane >> 4;
  const int stile = blockIdx.x, h = blockIdx.y, b = blockIdx.z;
  const int s0 = stile * 256 + wave * 16;

  const unsigned short* qrow = qsb + ((long)(b * S_) + s0 + l15) * D_ + h * 64 + quad * 8;
  bf8 a0 = ldb(qrow);
  bf8 a1 = ldb(qrow + 32);

  // staging decode (u = tid, 1024 units): l15=u&15, quad=(u>>4)&3, tt=(u>>6)&7, h2=u>>9
  const int sl15 = tid & 15, squad = (tid >> 4) & 3, stt = (tid >> 6) & 7, sh2 = tid >> 9;
  const unsigned short* gsrc0 =
      ksb + ((long)(b * S_) + stt * 16 + sl15) * D_ + h * 64 + sh2 * 32 + squad * 8;

  f4 sum = f4{0.f, 0.f, 0.f, 0.f};
  for (int t0 = 0; t0 < S_; t0 += 128) {
    stage16(gsrc0 + (long)t0 * D_, lds + tid * 8);
    __syncthreads();
#pragma unroll
    for (int tt = 0; tt < 8; ++tt) {
      bf8 b0 = ldb(lds + tt * 512 + lane * 8);
      bf8 b1 = ldb(lds + 4096 + tt * 512 + lane * 8);
      f4 d = f4{0.f, 0.f, 0.f, 0.f};
      d = MFMA(a0, b0, d);
      d = MFMA(a1, b1, d);
#pragma unroll
      for (int r = 0; r < 4; ++r) sum[r] += __builtin_amdgcn_exp2f(d[r]);
    }
    __syncthreads();
  }
#pragma unroll
  for (int m = 1; m < 16; m <<= 1) {
#pragma unroll
    for (int r = 0; r < 4; ++r) sum[r] += __shfl_xor(sum[r], m, 64);
  }
  if (l15 == 0) {
    float* rp = recip + (long)(b * H_ + h) * S_ + s0 + quad * 4;
#pragma unroll
    for (int r = 0; r < 4; ++r) rp[r] = 1.0f / (16.0f * sum[r]);
  }
}

// ---- pass 2: attn_mean[b,s,t] = sum_h recip[b,h,s]*exp2(score) ----
// grid (16 t-chunks of 128, 16 s-tiles of 128, B), block 512 (8 waves); fragment-major LDS
__global__ __launch_bounds__(512) void k_attn(
    const unsigned short* __restrict__ qsb, const unsigned short* __restrict__ ksb,
    const float* __restrict__ recip, float* __restrict__ am) {
  __shared__ unsigned short lds[8192];          // 128 t-rows x 64 dk per head
  const int tid = threadIdx.x, wave = tid >> 6, lane = tid & 63;
  const int l15 = lane & 15, quad = lane >> 4;
  const int tchunk = blockIdx.x, stile = blockIdx.y, b = blockIdx.z;
  const int s0 = stile * 128 + wave * 16;
  const int t0c = tchunk * 128;

  f4 acc[8];
#pragma unroll
  for (int tt = 0; tt < 8; ++tt) acc[tt] = f4{0.f, 0.f, 0.f, 0.f};

  const unsigned short* qbase = qsb + ((long)(b * S_) + s0 + l15) * D_ + quad * 8;

  // staging decode (u = i*512+tid, 1024 units)
  for (int h = 0; h < H_; ++h) {
#pragma unroll
    for (int i = 0; i < 2; ++i) {
      int u = i * 512 + tid;
      int sl15 = u & 15, squad = (u >> 4) & 3, stt = (u >> 6) & 7, sh2 = u >> 9;
      stage16(ksb + ((long)(b * S_) + t0c + stt * 16 + sl15) * D_ + h * 64 + sh2 * 32 + squad * 8,
              lds + u * 8);
    }
    bf8 a0 = ldb(qbase + h * 64);
    bf8 a1 = ldb(qbase + h * 64 + 32);
    f4 rp = *reinterpret_cast<const f4*>(recip + (long)(b * H_ + h) * S_ + s0 + quad * 4);
    __syncthreads();
#pragma unroll
    for (int tt = 0; tt < 8; ++tt) {
      bf8 b0 = ldb(lds + tt * 512 + lane * 8);
      bf8 b1 = ldb(lds + 4096 + tt * 512 + lane * 8);
      f4 d = f4{0.f, 0.f, 0.f, 0.f};
      d = MFMA(a0, b0, d);
      d = MFMA(a1, b1, d);
#pragma unroll
      for (int r = 0; r < 4; ++r) acc[tt][r] += rp[r] * __builtin_amdgcn_exp2f(d[r]);
    }
    __syncthreads();
  }
  float* obase = am + ((long)b * S_ + s0 + quad * 4) * S_ + t0c + l15;
#pragma unroll
  for (int tt = 0; tt < 8; ++tt)
#pragma unroll
    for (int r = 0; r < 4; ++r) obase[(long)r * S_ + tt * 16] = acc[tt][r];
}

// ---- head split-K: ph[kc][row][64] f32 = am-chunk @ vs-chunk, kc chunk = 512 t ----
// grid (64 rowgroups, 4 kc), block 256
__global__ __launch_bounds__(256) void k_hpart(
    const float* __restrict__ am, const unsigned short* __restrict__ vst,
    float* __restrict__ ph) {
  const int tid = threadIdx.x, wave = tid >> 6, lane = tid & 63;
  const int l15 = lane & 15, quad = lane >> 4;
  const int rg = blockIdx.x, kc = blockIdx.y;
  const int row0 = rg * 64 + wave * 16;
  const int b = row0 >> 11;
  const float* arow = am + (long)(row0 + l15) * S_ + kc * 512 + quad * 8;
  const unsigned short* vb = vst + (long)b * DK_ * S_ + kc * 512 + quad * 8;
  f4 acc[4];
  for (int i = 0; i < 4; ++i) acc[i] = f4{0.f, 0.f, 0.f, 0.f};
  for (int t0 = 0; t0 < 512; t0 += 32) {
    f4 alo = *reinterpret_cast<const f4*>(arow + t0);
    f4 ahi = *reinterpret_cast<const f4*>(arow + t0 + 4);
    bf8 a = pack_bf8(alo, ahi);
#pragma unroll
    for (int i = 0; i < 4; ++i) {
      bf8 bf = ldb(vb + (long)(i * 16 + l15) * S_ + t0);
      acc[i] = MFMA(a, bf, acc[i]);
    }
  }
#pragma unroll
  for (int i = 0; i < 4; ++i)
#pragma unroll
    for (int r = 0; r < 4; ++r)
      ph[((long)kc * 4096 + row0 + quad * 4 + r) * 64 + i * 16 + l15] = acc[i][r];
}

// reduce -> headb bf16 [row][64] (fully coalesced)
__global__ void k_hred(const float* __restrict__ ph, unsigned short* __restrict__ headb) {
  int e = blockIdx.x * 256 + threadIdx.x;      // e = row*64 + dk
  float s = ph[e] + ph[e + 4096 * 64] + ph[e + 2 * 4096 * 64] + ph[e + 3 * 4096 * 64];
  headb[e] = f2bf_bits(s);
}

// ---- out = head @ Wo ----
// grid (8 d-chunks of 128, 32 s-tiles of 64, B), block 256
__global__ __launch_bounds__(256) void k_out(
    const unsigned short* __restrict__ head, const unsigned short* __restrict__ wot,
    float* __restrict__ out) {
  const int tid = threadIdx.x, wave = tid >> 6, lane = tid & 63;
  const int l15 = lane & 15, quad = lane >> 4;
  const int dchunk = blockIdx.x, stile = blockIdx.y, b = blockIdx.z;
  const int s0 = stile * 64 + wave * 16;
  const int n0 = dchunk * 128;
  const unsigned short* hrow = head + ((long)b * S_ + s0 + l15) * DK_ + quad * 8;
  bf8 a0 = ldb(hrow);
  bf8 a1 = ldb(hrow + 32);
  const unsigned short* wb = wot + quad * 8;
  float* obase = out + ((long)b * S_ + s0 + quad * 4) * D_ + n0 + l15;
#pragma unroll
  for (int i = 0; i < 8; ++i) {
    const unsigned short* wp = wb + (long)(n0 + i * 16 + l15) * DK_;
    bf8 b0 = ldb(wp);
    bf8 b1 = ldb(wp + 32);
    f4 d = f4{0.f, 0.f, 0.f, 0.f};
    d = MFMA(a0, b0, d);
    d = MFMA(a1, b1, d);
#pragma unroll
    for (int r = 0; r < 4; ++r) obase[(long)r * D_ + i * 16] = d[r];
  }
}

extern "C" void kernel_launch(void* const* d_in, const int* in_sizes, int n_in,
                              void* d_out, int out_size, void* d_ws, size_t ws_size,
                              hipStream_t stream) {
  const float* q  = (const float*)d_in[0];
  const float* k  = (const float*)d_in[1];
  const float* v  = (const float*)d_in[2];
  const float* Wq = (const float*)d_in[3];
  const float* Wk = (const float*)d_in[4];
  const float* Wv = (const float*)d_in[5];
  const float* Wo = (const float*)d_in[6];

  float* out = (float*)d_out;                       // [B,S,D] = 4,194,304 f32
  float* am  = out + (long)B_ * S_ * D_;            // [B,S,S] = 8,388,608 f32

  // workspace (~22.5 MB)
  unsigned short* qsb  = (unsigned short*)d_ws;     // [4096][1024]
  unsigned short* ksb  = qsb + 4194304;
  unsigned short* wqt  = ksb + 4194304;             // [1024][1024]
  unsigned short* wkt  = wqt + 1048576;
  unsigned short* wvt  = wkt + 1048576;             // [64][1024]
  unsigned short* wot  = wvt + 65536;               // [1024][64]
  unsigned short* vst  = wot + 65536;               // [B][64][S]
  unsigned short* headb= vst + 262144;              // [4096][64]
  float* recip = (float*)(headb + 262144);          // [B*H*S]

  // bf16 q,k copies live in the am region of d_out (dead before k_attn writes am)
  unsigned short* qb = (unsigned short*)am;         // [4096][1024]
  unsigned short* kb = qb + 4194304;
  // split-K f32 partials [4][4096][64] live in the out region (dead until k_out)
  float* part = out;

  k_prep<<<8448, 256, 0, stream>>>(q, k, Wq, Wk, Wv, Wo, qb, kb, wqt, wkt, wvt, wot);
  k_gemm_qk<<<dim3(32, 16, 2), 256, 0, stream>>>(qb, kb, wqt, wkt, qsb, ksb);
  k_pv<<<dim3(64, 4), 256, 0, stream>>>(v, wvt, part);
  k_vred<<<1024, 256, 0, stream>>>(part, vst);
  k_denom<<<dim3(8, 16, 2), 1024, 0, stream>>>(qsb, ksb, recip);
  k_attn<<<dim3(16, 16, 2), 512, 0, stream>>>(qsb, ksb, recip, am);
  k_hpart<<<dim3(64, 4), 256, 0, stream>>>(am, vst, part);
  k_hred<<<1024, 256, 0, stream>>>(part, headb);
  k_out<<<dim3(8, 32, 2), 256, 0, stream>>>(headb, wot, out);
}

// Round 4
// 246.872 us; speedup vs baseline: 2.4013x; 1.0781x over previous
//
#include <hip/hip_runtime.h>

// B=2, S=2048, D=1024, H=16, DK=64
// out = attn_mean @ vs @ Wo  (Wv shared across heads => mean_h(attn_h @ vs) = attn_mean @ vs)
// attn_mean[b,s,t] = (1/H) sum_h exp(score)/denom  -- no max-subtraction (scores bounded ~|2.5|)
// qs/ks layout: [b*S+s][h*64+dk]  (concatenated-head GEMM output)
// All LDS tiles are FRAGMENT-MAJOR: 16B-unit index = tile*64 + quad*16 + l15
//   -> reader addr = tilebase + lane*16B, conflict-free for ds_read_b128.
#define B_ 2
#define S_ 2048
#define D_ 1024
#define H_ 16
#define DK_ 64

typedef __bf16 bf8 __attribute__((ext_vector_type(8)));
typedef float f4 __attribute__((ext_vector_type(4)));
typedef unsigned short u16x8 __attribute__((ext_vector_type(8)));

__device__ __forceinline__ unsigned short f2bf_bits(float f) {
  unsigned int u = __float_as_uint(f);
  return (unsigned short)((u + 0x7fffu + ((u >> 16) & 1u)) >> 16);
}

__device__ __forceinline__ bf8 pack_bf8(f4 lo, f4 hi) {
  u16x8 u;
  u[0] = f2bf_bits(lo[0]); u[1] = f2bf_bits(lo[1]);
  u[2] = f2bf_bits(lo[2]); u[3] = f2bf_bits(lo[3]);
  u[4] = f2bf_bits(hi[0]); u[5] = f2bf_bits(hi[1]);
  u[6] = f2bf_bits(hi[2]); u[7] = f2bf_bits(hi[3]);
  union { u16x8 u; bf8 b; } x; x.u = u; return x.b;
}

__device__ __forceinline__ bf8 ldb(const unsigned short* p) {
  return *reinterpret_cast<const bf8*>(p);
}

__device__ __forceinline__ void stage16(const void* g, void* l) {
  __builtin_amdgcn_global_load_lds(
      (const __attribute__((address_space(1))) void*)g,
      (__attribute__((address_space(3))) void*)l, 16, 0, 0);
}

#define MFMA(a, b, c) __builtin_amdgcn_mfma_f32_16x16x32_bf16((a), (b), (c), 0, 0, 0)

// ---- merged prep: cast q,k -> bf16 rows; LDS-tiled transpose-cast weights ----
// blocks 0..4095: cast q/k | 4096..4351: wq/wk 64x64 tiles | 4352..4367: wv | 4368..4383: wo
__global__ void k_prep(const float* __restrict__ q, const float* __restrict__ k,
                       const float* __restrict__ wq, const float* __restrict__ wk,
                       const float* __restrict__ wv, const float* __restrict__ wo,
                       unsigned short* __restrict__ qb, unsigned short* __restrict__ kb,
                       unsigned short* __restrict__ wqt, unsigned short* __restrict__ wkt,
                       unsigned short* __restrict__ wvt, unsigned short* __restrict__ wot) {
  __shared__ float tl[64 * 65];
  int bid = blockIdx.x, tid = threadIdx.x;
  const int rr = tid >> 6, cc = tid & 63;
  if (bid < 4096) {
    int which = bid >> 11;
    long i = ((long)(bid & 2047) * 256 + tid) * 8;
    const float* src = which ? k : q;
    unsigned short* dst = which ? kb : qb;
    f4 lo = *reinterpret_cast<const f4*>(src + i);
    f4 hi = *reinterpret_cast<const f4*>(src + i + 4);
    *reinterpret_cast<bf8*>(dst + i) = pack_bf8(lo, hi);
  } else if (bid < 4352) {
    // Wq/Wk [h][d][n=dk] -> [h][n][d], 64x64 f32 tile via LDS (coalesced both ways)
    int blk = bid - 4096;
    int h = blk >> 4, d0 = (blk & 15) * 64;
    for (int m = 0; m < 2; ++m) {
      const float* src = m ? wk : wq;
      unsigned short* dst = m ? wkt : wqt;
      if (m) __syncthreads();
#pragma unroll
      for (int it = 0; it < 16; ++it) {
        int d = it * 4 + rr;
        tl[cc * 65 + d] = src[(long)h * 65536 + (d0 + d) * 64 + cc];
      }
      __syncthreads();
#pragma unroll
      for (int it = 0; it < 16; ++it) {
        int n = it * 4 + rr;
        dst[(long)h * 65536 + n * 1024 + d0 + cc] = f2bf_bits(tl[n * 65 + cc]);
      }
    }
  } else if (bid < 4368) {
    // Wv [d][n=dk] -> [n][d]
    int d0 = (bid - 4352) * 64;
#pragma unroll
    for (int it = 0; it < 16; ++it) {
      int d = it * 4 + rr;
      tl[cc * 65 + d] = wv[(long)(d0 + d) * 64 + cc];
    }
    __syncthreads();
#pragma unroll
    for (int it = 0; it < 16; ++it) {
      int n = it * 4 + rr;
      wvt[(long)n * 1024 + d0 + cc] = f2bf_bits(tl[n * 65 + cc]);
    }
  } else {
    // Wo [kk][dd] -> [dd][kk]
    int d0 = (bid - 4368) * 64;
#pragma unroll
    for (int it = 0; it < 16; ++it) {
      int kk = it * 4 + rr;
      tl[cc * 65 + kk] = wo[(long)kk * 1024 + d0 + cc];   // tl[ddl][kk]
    }
    __syncthreads();
#pragma unroll
    for (int it = 0; it < 16; ++it) {
      int ddl = it * 4 + rr;
      wot[(long)(d0 + ddl) * 64 + cc] = f2bf_bits(tl[ddl * 65 + cc]);
    }
  }
}

// ---- GEMM: C[4096][1024] = X @ W^T, 128x128 tile, BK=32, fragment-major LDS (m97 geometry) ----
// grid (32 m-tiles, 8 n-tiles, which), block 256 (4 waves 2x2; wave = 64m x 64n, 4x4 MFMA)
__global__ __launch_bounds__(256) void k_gemm_qk(
    const unsigned short* __restrict__ qb, const unsigned short* __restrict__ kb,
    const unsigned short* __restrict__ wqt, const unsigned short* __restrict__ wkt,
    unsigned short* __restrict__ qsb, unsigned short* __restrict__ ksb) {
  __shared__ unsigned short lds[8192];          // A 8 tiles @0 (tile*512), B 8 tiles @4096
  const int tid = threadIdx.x, wave = tid >> 6, lane = tid & 63;
  const int l15 = lane & 15, quad = lane >> 4;
  const int m0 = blockIdx.x * 128, n0 = blockIdx.y * 128;
  const int which = blockIdx.z;
  const unsigned short* A = which ? kb : qb;
  const unsigned short* W = which ? wkt : wqt;
  unsigned short* C = which ? ksb : qsb;
  const float scale = which ? 1.0f : 0.18033688011112042f;  // log2(e)/8 folded into qs
  const int wr = wave >> 1, wc = wave & 1;

  f4 acc[4][4];
#pragma unroll
  for (int i = 0; i < 4; ++i)
#pragma unroll
    for (int j = 0; j < 4; ++j) acc[i][j] = f4{0.f, 0.f, 0.f, 0.f};

  // staging decode: u = i*256+tid; tile=u>>6 (st + i*4), quad=(u>>4)&3, l15=u&15
  const int sl15 = tid & 15, squad = (tid >> 4) & 3, st = tid >> 6;
  const unsigned short* gA = A + (long)(m0 + st * 16 + sl15) * D_ + squad * 8;
  const unsigned short* gB = W + (long)(n0 + st * 16 + sl15) * D_ + squad * 8;

  for (int k0 = 0; k0 < D_; k0 += 32) {
    stage16(gA + k0, lds + tid * 8);                       // A tiles 0..3
    stage16(gA + 64 * D_ + k0, lds + 2048 + tid * 8);      // A tiles 4..7
    stage16(gB + k0, lds + 4096 + tid * 8);                // B tiles 0..3
    stage16(gB + 64 * D_ + k0, lds + 6144 + tid * 8);      // B tiles 4..7
    __syncthreads();
    bf8 aF[4], bF[4];
#pragma unroll
    for (int mi = 0; mi < 4; ++mi)
      aF[mi] = ldb(lds + (wr * 4 + mi) * 512 + lane * 8);
#pragma unroll
    for (int ni = 0; ni < 4; ++ni)
      bF[ni] = ldb(lds + 4096 + (wc * 4 + ni) * 512 + lane * 8);
#pragma unroll
    for (int mi = 0; mi < 4; ++mi)
#pragma unroll
      for (int ni = 0; ni < 4; ++ni)
        acc[mi][ni] = MFMA(aF[mi], bF[ni], acc[mi][ni]);
    __syncthreads();
  }
#pragma unroll
  for (int mi = 0; mi < 4; ++mi)
#pragma unroll
    for (int r = 0; r < 4; ++r) {
      long row = m0 + wr * 64 + mi * 16 + quad * 4 + r;
#pragma unroll
      for (int ni = 0; ni < 4; ++ni)
        C[row * D_ + n0 + wc * 64 + ni * 16 + l15] = f2bf_bits(acc[mi][ni][r] * scale);
    }
}

// ---- V projection split-K: partial[kc][row][64] f32, kc chunk = 256 ----
// grid (64 rowgroups of 64, 4 kc), block 256
__global__ __launch_bounds__(256) void k_pv(
    const float* __restrict__ v, const unsigned short* __restrict__ wvt,
    float* __restrict__ pv) {
  const int tid = threadIdx.x, wave = tid >> 6, lane = tid & 63;
  const int l15 = lane & 15, quad = lane >> 4;
  const int rg = blockIdx.x, kc = blockIdx.y;
  const int row0 = rg * 64 + wave * 16;
  const float* arow = v + (long)(row0 + l15) * D_ + kc * 256 + quad * 8;
  const unsigned short* wbase = wvt + kc * 256 + quad * 8;
  f4 acc[4];
  for (int i = 0; i < 4; ++i) acc[i] = f4{0.f, 0.f, 0.f, 0.f};
  for (int k0 = 0; k0 < 256; k0 += 32) {
    f4 alo = *reinterpret_cast<const f4*>(arow + k0);
    f4 ahi = *reinterpret_cast<const f4*>(arow + k0 + 4);
    bf8 a = pack_bf8(alo, ahi);
#pragma unroll
    for (int i = 0; i < 4; ++i) {
      bf8 bf = ldb(wbase + (long)(i * 16 + l15) * D_ + k0);
      acc[i] = MFMA(a, bf, acc[i]);
    }
  }
#pragma unroll
  for (int i = 0; i < 4; ++i)
#pragma unroll
    for (int r = 0; r < 4; ++r)
      pv[((long)kc * 4096 + row0 + quad * 4 + r) * 64 + i * 16 + l15] = acc[i][r];
}

// reduce 4 k-partials -> vst[b][dk][t] bf16 (writes coalesced over t)
__global__ void k_vred(const float* __restrict__ pv, unsigned short* __restrict__ vst) {
  int e = blockIdx.x * 256 + threadIdx.x;      // e = (b*64+dk)*2048 + t
  int t = e & 2047, dk = (e >> 11) & 63, b = e >> 17;
  long row = (long)b * S_ + t;
  float s = pv[row * 64 + dk] + pv[(4096 + row) * 64 + dk] +
            pv[(8192 + row) * 64 + dk] + pv[(12288 + row) * 64 + dk];
  vst[e] = f2bf_bits(s);
}

// ---- pass 1: recip[b,h,s] = 1/(H * sum_t exp2(qs.ks)) ----
// grid (16 s-tiles of 128, H, B), block 512 (8 waves); K-chunks of 128, fragment-major
__global__ __launch_bounds__(512) void k_denom(
    const unsigned short* __restrict__ qsb, const unsigned short* __restrict__ ksb,
    float* __restrict__ recip) {
  __shared__ unsigned short lds[8192];          // 128 t-rows x 64 dk, fragment-major
  const int tid = threadIdx.x, wave = tid >> 6, lane = tid & 63;
  const int l15 = lane & 15, quad = lane >> 4;
  const int stile = blockIdx.x, h = blockIdx.y, b = blockIdx.z;
  const int s0 = stile * 128 + wave * 16;

  const unsigned short* qrow = qsb + ((long)(b * S_) + s0 + l15) * D_ + h * 64 + quad * 8;
  bf8 a0 = ldb(qrow);
  bf8 a1 = ldb(qrow + 32);

  f4 sum = f4{0.f, 0.f, 0.f, 0.f};
  for (int t0 = 0; t0 < S_; t0 += 128) {
#pragma unroll
    for (int i = 0; i < 2; ++i) {
      int u = i * 512 + tid;
      int sl15 = u & 15, squad = (u >> 4) & 3, stt = (u >> 6) & 7, sh2 = u >> 9;
      stage16(ksb + ((long)(b * S_) + t0 + stt * 16 + sl15) * D_ + h * 64 + sh2 * 32 + squad * 8,
              lds + u * 8);
    }
    __syncthreads();
#pragma unroll
    for (int tt = 0; tt < 8; ++tt) {
      bf8 b0 = ldb(lds + tt * 512 + lane * 8);
      bf8 b1 = ldb(lds + 4096 + tt * 512 + lane * 8);
      f4 d = f4{0.f, 0.f, 0.f, 0.f};
      d = MFMA(a0, b0, d);
      d = MFMA(a1, b1, d);
#pragma unroll
      for (int r = 0; r < 4; ++r) sum[r] += __builtin_amdgcn_exp2f(d[r]);
    }
    __syncthreads();
  }
#pragma unroll
  for (int m = 1; m < 16; m <<= 1) {
#pragma unroll
    for (int r = 0; r < 4; ++r) sum[r] += __shfl_xor(sum[r], m, 64);
  }
  if (l15 == 0) {
    float* rp = recip + (long)(b * H_ + h) * S_ + s0 + quad * 4;
#pragma unroll
    for (int r = 0; r < 4; ++r) rp[r] = 1.0f / (16.0f * sum[r]);
  }
}

// ---- pass 2: attn_mean[b,s,t] = sum_h recip[b,h,s]*exp2(score) ----
// grid (16 t-chunks of 128, 16 s-tiles of 128, B), block 512 (8 waves); fragment-major LDS
__global__ __launch_bounds__(512) void k_attn(
    const unsigned short* __restrict__ qsb, const unsigned short* __restrict__ ksb,
    const float* __restrict__ recip, float* __restrict__ am) {
  __shared__ unsigned short lds[8192];          // 128 t-rows x 64 dk per head
  const int tid = threadIdx.x, wave = tid >> 6, lane = tid & 63;
  const int l15 = lane & 15, quad = lane >> 4;
  const int tchunk = blockIdx.x, stile = blockIdx.y, b = blockIdx.z;
  const int s0 = stile * 128 + wave * 16;
  const int t0c = tchunk * 128;

  f4 acc[8];
#pragma unroll
  for (int tt = 0; tt < 8; ++tt) acc[tt] = f4{0.f, 0.f, 0.f, 0.f};

  const unsigned short* qbase = qsb + ((long)(b * S_) + s0 + l15) * D_ + quad * 8;

  for (int h = 0; h < H_; ++h) {
#pragma unroll
    for (int i = 0; i < 2; ++i) {
      int u = i * 512 + tid;
      int sl15 = u & 15, squad = (u >> 4) & 3, stt = (u >> 6) & 7, sh2 = u >> 9;
      stage16(ksb + ((long)(b * S_) + t0c + stt * 16 + sl15) * D_ + h * 64 + sh2 * 32 + squad * 8,
              lds + u * 8);
    }
    bf8 a0 = ldb(qbase + h * 64);
    bf8 a1 = ldb(qbase + h * 64 + 32);
    f4 rp = *reinterpret_cast<const f4*>(recip + (long)(b * H_ + h) * S_ + s0 + quad * 4);
    __syncthreads();
#pragma unroll
    for (int tt = 0; tt < 8; ++tt) {
      bf8 b0 = ldb(lds + tt * 512 + lane * 8);
      bf8 b1 = ldb(lds + 4096 + tt * 512 + lane * 8);
      f4 d = f4{0.f, 0.f, 0.f, 0.f};
      d = MFMA(a0, b0, d);
      d = MFMA(a1, b1, d);
#pragma unroll
      for (int r = 0; r < 4; ++r) acc[tt][r] += rp[r] * __builtin_amdgcn_exp2f(d[r]);
    }
    __syncthreads();
  }
  float* obase = am + ((long)b * S_ + s0 + quad * 4) * S_ + t0c + l15;
#pragma unroll
  for (int tt = 0; tt < 8; ++tt)
#pragma unroll
    for (int r = 0; r < 4; ++r) obase[(long)r * S_ + tt * 16] = acc[tt][r];
}

// ---- head split-K: ph[kc][row][64] f32 = am-chunk @ vs-chunk, kc chunk = 512 t ----
// grid (64 rowgroups, 4 kc), block 256
__global__ __launch_bounds__(256) void k_hpart(
    const float* __restrict__ am, const unsigned short* __restrict__ vst,
    float* __restrict__ ph) {
  const int tid = threadIdx.x, wave = tid >> 6, lane = tid & 63;
  const int l15 = lane & 15, quad = lane >> 4;
  const int rg = blockIdx.x, kc = blockIdx.y;
  const int row0 = rg * 64 + wave * 16;
  const int b = row0 >> 11;
  const float* arow = am + (long)(row0 + l15) * S_ + kc * 512 + quad * 8;
  const unsigned short* vb = vst + (long)b * DK_ * S_ + kc * 512 + quad * 8;
  f4 acc[4];
  for (int i = 0; i < 4; ++i) acc[i] = f4{0.f, 0.f, 0.f, 0.f};
  for (int t0 = 0; t0 < 512; t0 += 32) {
    f4 alo = *reinterpret_cast<const f4*>(arow + t0);
    f4 ahi = *reinterpret_cast<const f4*>(arow + t0 + 4);
    bf8 a = pack_bf8(alo, ahi);
#pragma unroll
    for (int i = 0; i < 4; ++i) {
      bf8 bf = ldb(vb + (long)(i * 16 + l15) * S_ + t0);
      acc[i] = MFMA(a, bf, acc[i]);
    }
  }
#pragma unroll
  for (int i = 0; i < 4; ++i)
#pragma unroll
    for (int r = 0; r < 4; ++r)
      ph[((long)kc * 4096 + row0 + quad * 4 + r) * 64 + i * 16 + l15] = acc[i][r];
}

// reduce -> headb bf16 [row][64] (fully coalesced)
__global__ void k_hred(const float* __restrict__ ph, unsigned short* __restrict__ headb) {
  int e = blockIdx.x * 256 + threadIdx.x;      // e = row*64 + dk
  float s = ph[e] + ph[e + 4096 * 64] + ph[e + 2 * 4096 * 64] + ph[e + 3 * 4096 * 64];
  headb[e] = f2bf_bits(s);
}

// ---- out = head @ Wo ----
// grid (8 d-chunks of 128, 32 s-tiles of 64, B), block 256
__global__ __launch_bounds__(256) void k_out(
    const unsigned short* __restrict__ head, const unsigned short* __restrict__ wot,
    float* __restrict__ out) {
  const int tid = threadIdx.x, wave = tid >> 6, lane = tid & 63;
  const int l15 = lane & 15, quad = lane >> 4;
  const int dchunk = blockIdx.x, stile = blockIdx.y, b = blockIdx.z;
  const int s0 = stile * 64 + wave * 16;
  const int n0 = dchunk * 128;
  const unsigned short* hrow = head + ((long)b * S_ + s0 + l15) * DK_ + quad * 8;
  bf8 a0 = ldb(hrow);
  bf8 a1 = ldb(hrow + 32);
  const unsigned short* wb = wot + quad * 8;
  float* obase = out + ((long)b * S_ + s0 + quad * 4) * D_ + n0 + l15;
#pragma unroll
  for (int i = 0; i < 8; ++i) {
    const unsigned short* wp = wb + (long)(n0 + i * 16 + l15) * DK_;
    bf8 b0 = ldb(wp);
    bf8 b1 = ldb(wp + 32);
    f4 d = f4{0.f, 0.f, 0.f, 0.f};
    d = MFMA(a0, b0, d);
    d = MFMA(a1, b1, d);
#pragma unroll
    for (int r = 0; r < 4; ++r) obase[(long)r * D_ + i * 16] = d[r];
  }
}

extern "C" void kernel_launch(void* const* d_in, const int* in_sizes, int n_in,
                              void* d_out, int out_size, void* d_ws, size_t ws_size,
                              hipStream_t stream) {
  const float* q  = (const float*)d_in[0];
  const float* k  = (const float*)d_in[1];
  const float* v  = (const float*)d_in[2];
  const float* Wq = (const float*)d_in[3];
  const float* Wk = (const float*)d_in[4];
  const float* Wv = (const float*)d_in[5];
  const float* Wo = (const float*)d_in[6];

  float* out = (float*)d_out;                       // [B,S,D] = 4,194,304 f32
  float* am  = out + (long)B_ * S_ * D_;            // [B,S,S] = 8,388,608 f32

  // workspace (~22.5 MB)
  unsigned short* qsb  = (unsigned short*)d_ws;     // [4096][1024]
  unsigned short* ksb  = qsb + 4194304;
  unsigned short* wqt  = ksb + 4194304;             // [1024][1024]
  unsigned short* wkt  = wqt + 1048576;
  unsigned short* wvt  = wkt + 1048576;             // [64][1024]
  unsigned short* wot  = wvt + 65536;               // [1024][64]
  unsigned short* vst  = wot + 65536;               // [B][64][S]
  unsigned short* headb= vst + 262144;              // [4096][64]
  float* recip = (float*)(headb + 262144);          // [B*H*S]

  // bf16 q,k copies live in the am region of d_out (dead before k_attn writes am)
  unsigned short* qb = (unsigned short*)am;         // [4096][1024]
  unsigned short* kb = qb + 4194304;
  // split-K f32 partials [4][4096][64] live in the out region (dead until k_out)
  float* part = out;

  k_prep<<<4384, 256, 0, stream>>>(q, k, Wq, Wk, Wv, Wo, qb, kb, wqt, wkt, wvt, wot);
  k_gemm_qk<<<dim3(32, 8, 2), 256, 0, stream>>>(qb, kb, wqt, wkt, qsb, ksb);
  k_pv<<<dim3(64, 4), 256, 0, stream>>>(v, wvt, part);
  k_vred<<<1024, 256, 0, stream>>>(part, vst);
  k_denom<<<dim3(16, 16, 2), 512, 0, stream>>>(qsb, ksb, recip);
  k_attn<<<dim3(16, 16, 2), 512, 0, stream>>>(qsb, ksb, recip, am);
  k_hpart<<<dim3(64, 4), 256, 0, stream>>>(am, vst, part);
  k_hred<<<1024, 256, 0, stream>>>(part, headb);
  k_out<<<dim3(8, 32, 2), 256, 0, stream>>>(headb, wot, out);
}